// Round 1
// baseline (232.246 us; speedup 1.0000x reference)
//
#include <hip/hip_runtime.h>
#include <math.h>

#define B 4
#define P 32768
#define C 8
#define F 32
#define D 64
#define H 64
#define RS 72   // LDS row stride in shorts

typedef __attribute__((ext_vector_type(8))) short bf16x8;
typedef __attribute__((ext_vector_type(4))) float f32x4;

__device__ __forceinline__ short f2bf(float f) {
    union { float f; unsigned u; } v; v.f = f;
    unsigned r = (v.u + 0x7FFFu + ((v.u >> 16) & 1u)) >> 16;   // RNE
    return (short)r;
}

// packed f32x2 -> bf16x2 (RNE) in one VALU op (T12 recipe; no builtin on gfx950)
__device__ __forceinline__ unsigned cvt_pk_bf16(float lo, float hi) {
    unsigned r;
    asm("v_cvt_pk_bf16_f32 %0, %1, %2" : "=v"(r) : "v"(lo), "v"(hi));
    return r;
}

// ---------------------------------------------------------------------------
// Merged setup kernel.
// blocks [0,32):  per-(b,c) Bxt build (K<=33 rows: ZW, W0-row0, zc; rest 0)
// blocks [32,112): Wa/Wb transpose+cvt to n-major bf16
// All n-major weight storage uses the COLUMN PERMUTATION: storage row
// s = (a%4)*16 + a/4  holds actual output column a (makes the MFMA C-layout's
// 4 per-lane values memory-adjacent for the b64 LDS transform).
// W_dir/W0 columns are hoisted to per-thread registers (was: 1024 global
// loads/thread in the inner loop).
// ---------------------------------------------------------------------------
__global__ __launch_bounds__(256)
void setup_kernel(const float* __restrict__ z,
                  const float* __restrict__ W_dir,
                  const float* __restrict__ W0,
                  const float* __restrict__ b0,
                  const float* __restrict__ Wa,
                  const float* __restrict__ Wb,
                  short* __restrict__ Bxt,
                  short* __restrict__ Wat,
                  short* __restrict__ Wbt)
{
    if (blockIdx.x >= 32) {
        int idx = (blockIdx.x - 32) * 256 + threadIdx.x;  // < 5*64*64
        int i = idx >> 12, r = idx & 4095, k = r >> 6, n = r & 63;
        int s = (n & 3) * 16 + (n >> 2);                  // permuted storage row
        int o = (i << 12) + (s << 6) + k;
        Wat[o] = f2bf(Wa[idx]);
        Wbt[o] = f2bf(Wb[idx]);
        return;
    }
    const int bc = blockIdx.x;
    const int t  = threadIdx.x & 63;     // actual output column
    const int g  = threadIdx.x >> 6;     // f-group 0..3
    const float* zb = z + (size_t)bc * F * D;

    __shared__ float zl[F][D];
    __shared__ float zp[4][D];

    for (int i = threadIdx.x; i < F * D; i += 256) zl[i >> 6][i & 63] = zb[i];

    // hoist weight columns t into registers (statically indexed -> VGPRs)
    float wdc[D], w0c[D];
#pragma unroll
    for (int d = 0; d < D; ++d) {
        wdc[d] = W_dir[d * D + t];
        w0c[d] = W0[(1 + d) * H + t];
    }
    __syncthreads();

    const int srow = (t & 3) * 16 + (t >> 2);
    short* brow = Bxt + ((size_t)bc * 64 + srow) * 64;

    float zi = 0.f;
    for (int f = g * 8; f < g * 8 + 8; ++f) {
        float z0 = 0, z1 = 0, z2 = 0, z3 = 0;
        float a0 = 0, a1 = 0, a2 = 0, a3 = 0;
#pragma unroll
        for (int d = 0; d < D; d += 4) {
            z0 += zl[f][d + 0] * wdc[d + 0];
            z1 += zl[f][d + 1] * wdc[d + 1];
            z2 += zl[f][d + 2] * wdc[d + 2];
            z3 += zl[f][d + 3] * wdc[d + 3];
            a0 += zl[f][d + 0] * w0c[d + 0];
            a1 += zl[f][d + 1] * w0c[d + 1];
            a2 += zl[f][d + 2] * w0c[d + 2];
            a3 += zl[f][d + 3] * w0c[d + 3];
        }
        zi += zl[f][t] * ((z0 + z1) + (z2 + z3));
        brow[f] = f2bf((a0 + a1) + (a2 + a3));    // ZW row f, col t (K natural)
    }
    zp[g][t] = zi;
    __syncthreads();
    if (g == 0) {
        float zall = zp[0][t] + zp[1][t] + zp[2][t] + zp[3][t];
        zp[0][t] = zall;                          // full z_inv[t]
    }
    __syncthreads();
    if (g == 0) {
        brow[32] = f2bf(W0[t]);                   // multiplies s2
        float zc = b0[t];
        for (int e = 0; e < D; ++e) zc += zp[0][e] * W0[(65 + e) * H + t];
        brow[33] = f2bf(zc);                      // multiplies 1
    } else if (g == 1) {
        for (int k = 34; k < 64; ++k) brow[k] = 0;
    }
}

// ---------------------------------------------------------------------------
// Main: 4 waves/block; each wave owns 32 points (2 m-tiles), ONE channel per
// c-iter (2 chains). Halving the chain count cuts transient VGPRs
// (x[2][4]+h[2][4] = 64 vs 128) so __launch_bounds__(256,3) fits 3 waves/SIMD
// -> latency stalls at stage boundaries hidden by TLP instead of ILP.
// C-layout -> A-layout transform: 4 x b64 LDS writes (col-permuted storage)
// + 2 x ds_read_b128 per tile-stage. No barriers (per-wave LDS; in-order DS).
// All f32->bf16 via v_cvt_pk_bf16_f32 (1 op / 2 elems vs 4 ops/elem manual).
// ---------------------------------------------------------------------------
__global__ __launch_bounds__(256, 3)
void main_kernel(const float* __restrict__ p,      // (B,P,3)
                 const float* __restrict__ pos,    // (B,3)
                 const float* __restrict__ W_feat, // (3,F)
                 const short* __restrict__ Bxt,    // (B,C,64s,64k) bf16 (perm cols)
                 const short* __restrict__ Wat,    // (5,64s,64k)
                 const short* __restrict__ Wbt,    // (5,64s,64k)
                 const float* __restrict__ ba,     // (5,H)
                 const float* __restrict__ bb,     // (5,H)
                 const float* __restrict__ Wout,   // (H,1)
                 const float* __restrict__ bout,   // (1,)
                 float* __restrict__ out)          // (B,P)
{
    const int wave = threadIdx.x >> 6;
    const int lane = threadIdx.x & 63;
    const int quad = lane >> 4;
    const int l16  = lane & 15;
    const int b    = blockIdx.y;
    const int base = blockIdx.x * 128 + wave * 32;

    __shared__ short lds[4][2][16 * RS];          // [wave][m-chain] = 18.4 KB

    // ---- point features -> A'-frags for both m-tiles
    bf16x8 a0[2], a1[2];
#pragma unroll
    for (int m = 0; m < 2; ++m) {
        const float* pp = p + ((size_t)b * P + base + m * 16 + l16) * 3;
        float px = pp[0] - pos[b * 3 + 0];
        float py = pp[1] - pos[b * 3 + 1];
        float pz = pp[2] - pos[b * 3 + 2];
        float nrm = sqrtf(px * px + py * py + pz * pz);
        if (nrm > 0.5f) { float s = 0.5f / nrm; px *= s; py *= s; pz *= s; }
        float av[8];
        float s2 = 0.f;
#pragma unroll
        for (int j = 0; j < 8; ++j) {
            int k = quad * 8 + j;
            av[j] = px * W_feat[k] + py * W_feat[F + k] + pz * W_feat[2 * F + k];
            s2 += av[j] * av[j];
        }
        s2 += __shfl_xor(s2, 16);
        s2 += __shfl_xor(s2, 32);
        union { bf16x8 v; unsigned u[4]; } ua;
#pragma unroll
        for (int j = 0; j < 4; ++j) ua.u[j] = cvt_pk_bf16(av[2 * j], av[2 * j + 1]);
        a0[m] = ua.v;
        union { bf16x8 v; unsigned u[4]; } ub;
#pragma unroll
        for (int j = 0; j < 4; ++j) ub.u[j] = 0;
        if (quad == 0) ub.u[0] = cvt_pk_bf16(s2, 1.0f);
        a1[m] = ub.v;
    }

    f32x4 pooled[2][4];
#pragma unroll
    for (int m = 0; m < 2; ++m)
#pragma unroll
        for (int nt = 0; nt < 4; ++nt)
            pooled[m][nt] = (f32x4){-1e30f, -1e30f, -1e30f, -1e30f};

    const float4 ba0v = *(const float4*)(ba + 4 * l16);
    const float4 bb0v = *(const float4*)(bb + 4 * l16);

    // =============== c-loop: 1 channel per iter, 2 m-chains =================
    for (int c = 0; c < C; ++c) {
        const short* bx = Bxt + ((size_t)(b * C + c)) * 4096;

        // ---- stage 1: x-build
        f32x4 x[2][4];
#pragma unroll
        for (int nt = 0; nt < 4; ++nt) {
            bf16x8 b0f = *(const bf16x8*)(bx + (nt * 16 + l16) * 64 + quad * 8);
            bf16x8 b1f = *(const bf16x8*)(bx + (nt * 16 + l16) * 64 + 32 + quad * 8);
#pragma unroll
            for (int m = 0; m < 2; ++m) {
                f32x4 acc = (f32x4){0.f, 0.f, 0.f, 0.f};
                acc = __builtin_amdgcn_mfma_f32_16x16x32_bf16(a0[m], b0f, acc, 0, 0, 0);
                acc = __builtin_amdgcn_mfma_f32_16x16x32_bf16(a1[m], b1f, acc, 0, 0, 0);
                x[m][nt] = acc;
            }
        }

        // ---- relu(x) -> LDS (b64 writes) -> A-frags
        bf16x8 xa0[2], xa1[2];
#pragma unroll
        for (int m = 0; m < 2; ++m) {
            short* buf = &lds[wave][m][0];
#pragma unroll
            for (int r = 0; r < 4; ++r) {
                uint2 w2;
                w2.x = cvt_pk_bf16(fmaxf(x[m][0][r], 0.f), fmaxf(x[m][1][r], 0.f));
                w2.y = cvt_pk_bf16(fmaxf(x[m][2][r], 0.f), fmaxf(x[m][3][r], 0.f));
                *(uint2*)(buf + (quad * 4 + r) * RS + 4 * l16) = w2;
            }
        }
#pragma unroll
        for (int m = 0; m < 2; ++m) {
            const short* buf = &lds[wave][m][0];
            xa0[m] = *(const bf16x8*)(buf + l16 * RS + quad * 8);
            xa1[m] = *(const bf16x8*)(buf + l16 * RS + 32 + quad * 8);
        }

        // ---- stage 2: h = relu(x) @ Wa0 + ba0
        f32x4 h[2][4];
#pragma unroll
        for (int nt = 0; nt < 4; ++nt) {
            bf16x8 w0f = *(const bf16x8*)(Wat + (nt * 16 + l16) * 64 + quad * 8);
            bf16x8 w1f = *(const bf16x8*)(Wat + (nt * 16 + l16) * 64 + 32 + quad * 8);
            float bv = nt == 0 ? ba0v.x : nt == 1 ? ba0v.y : nt == 2 ? ba0v.z : ba0v.w;
#pragma unroll
            for (int m = 0; m < 2; ++m) {
                f32x4 acc = (f32x4){bv, bv, bv, bv};
                acc = __builtin_amdgcn_mfma_f32_16x16x32_bf16(xa0[m], w0f, acc, 0, 0, 0);
                acc = __builtin_amdgcn_mfma_f32_16x16x32_bf16(xa1[m], w1f, acc, 0, 0, 0);
                h[m][nt] = acc;
            }
        }

        // ---- relu(h) -> LDS (reuse bufs; DS pipe is in-order per wave)
        bf16x8 ha0[2], ha1[2];
#pragma unroll
        for (int m = 0; m < 2; ++m) {
            short* buf = &lds[wave][m][0];
#pragma unroll
            for (int r = 0; r < 4; ++r) {
                uint2 w2;
                w2.x = cvt_pk_bf16(fmaxf(h[m][0][r], 0.f), fmaxf(h[m][1][r], 0.f));
                w2.y = cvt_pk_bf16(fmaxf(h[m][2][r], 0.f), fmaxf(h[m][3][r], 0.f));
                *(uint2*)(buf + (quad * 4 + r) * RS + 4 * l16) = w2;
            }
        }
#pragma unroll
        for (int m = 0; m < 2; ++m) {
            const short* buf = &lds[wave][m][0];
            ha0[m] = *(const bf16x8*)(buf + l16 * RS + quad * 8);
            ha1[m] = *(const bf16x8*)(buf + l16 * RS + 32 + quad * 8);
        }

        // ---- stage 3: x += bb0 + relu(h) @ Wb0 ; max-pool over c
#pragma unroll
        for (int nt = 0; nt < 4; ++nt) {
            bf16x8 w0f = *(const bf16x8*)(Wbt + (nt * 16 + l16) * 64 + quad * 8);
            bf16x8 w1f = *(const bf16x8*)(Wbt + (nt * 16 + l16) * 64 + 32 + quad * 8);
            float bv = nt == 0 ? bb0v.x : nt == 1 ? bb0v.y : nt == 2 ? bb0v.z : bb0v.w;
#pragma unroll
            for (int m = 0; m < 2; ++m) {
                f32x4 acc = x[m][nt];
#pragma unroll
                for (int r = 0; r < 4; ++r) acc[r] += bv;
                acc = __builtin_amdgcn_mfma_f32_16x16x32_bf16(ha0[m], w0f, acc, 0, 0, 0);
                acc = __builtin_amdgcn_mfma_f32_16x16x32_bf16(ha1[m], w1f, acc, 0, 0, 0);
#pragma unroll
                for (int r = 0; r < 4; ++r)
                    pooled[m][nt][r] = fmaxf(pooled[m][nt][r], acc[r]);
            }
        }
    }

    // =============== residual blocks 1..4 (2 chains: m-tiles) ===============
#pragma unroll
    for (int i = 1; i < 5; ++i) {
        const short* wa = Wat + i * 4096;
        const short* wb = Wbt + i * 4096;
        const float4 bai = *(const float4*)(ba + i * H + 4 * l16);
        const float4 bbi = *(const float4*)(bb + i * H + 4 * l16);

        bf16x8 xa0[2], xa1[2];
#pragma unroll
        for (int m = 0; m < 2; ++m) {
            short* buf = &lds[wave][m][0];
#pragma unroll
            for (int r = 0; r < 4; ++r) {
                uint2 w2;
                w2.x = cvt_pk_bf16(fmaxf(pooled[m][0][r], 0.f), fmaxf(pooled[m][1][r], 0.f));
                w2.y = cvt_pk_bf16(fmaxf(pooled[m][2][r], 0.f), fmaxf(pooled[m][3][r], 0.f));
                *(uint2*)(buf + (quad * 4 + r) * RS + 4 * l16) = w2;
            }
        }
#pragma unroll
        for (int m = 0; m < 2; ++m) {
            const short* buf = &lds[wave][m][0];
            xa0[m] = *(const bf16x8*)(buf + l16 * RS + quad * 8);
            xa1[m] = *(const bf16x8*)(buf + l16 * RS + 32 + quad * 8);
        }

        f32x4 h[2][4];
#pragma unroll
        for (int nt = 0; nt < 4; ++nt) {
            bf16x8 w0f = *(const bf16x8*)(wa + (nt * 16 + l16) * 64 + quad * 8);
            bf16x8 w1f = *(const bf16x8*)(wa + (nt * 16 + l16) * 64 + 32 + quad * 8);
            float bv = nt == 0 ? bai.x : nt == 1 ? bai.y : nt == 2 ? bai.z : bai.w;
#pragma unroll
            for (int m = 0; m < 2; ++m) {
                f32x4 acc = (f32x4){bv, bv, bv, bv};
                acc = __builtin_amdgcn_mfma_f32_16x16x32_bf16(xa0[m], w0f, acc, 0, 0, 0);
                acc = __builtin_amdgcn_mfma_f32_16x16x32_bf16(xa1[m], w1f, acc, 0, 0, 0);
                h[m][nt] = acc;
            }
        }

        bf16x8 ha0[2], ha1[2];
#pragma unroll
        for (int m = 0; m < 2; ++m) {
            short* buf = &lds[wave][m][0];
#pragma unroll
            for (int r = 0; r < 4; ++r) {
                uint2 w2;
                w2.x = cvt_pk_bf16(fmaxf(h[m][0][r], 0.f), fmaxf(h[m][1][r], 0.f));
                w2.y = cvt_pk_bf16(fmaxf(h[m][2][r], 0.f), fmaxf(h[m][3][r], 0.f));
                *(uint2*)(buf + (quad * 4 + r) * RS + 4 * l16) = w2;
            }
        }
#pragma unroll
        for (int m = 0; m < 2; ++m) {
            const short* buf = &lds[wave][m][0];
            ha0[m] = *(const bf16x8*)(buf + l16 * RS + quad * 8);
            ha1[m] = *(const bf16x8*)(buf + l16 * RS + 32 + quad * 8);
        }

#pragma unroll
        for (int nt = 0; nt < 4; ++nt) {
            bf16x8 w0f = *(const bf16x8*)(wb + (nt * 16 + l16) * 64 + quad * 8);
            bf16x8 w1f = *(const bf16x8*)(wb + (nt * 16 + l16) * 64 + 32 + quad * 8);
            float bv = nt == 0 ? bbi.x : nt == 1 ? bbi.y : nt == 2 ? bbi.z : bbi.w;
#pragma unroll
            for (int m = 0; m < 2; ++m) {
                f32x4 acc = pooled[m][nt];
#pragma unroll
                for (int r = 0; r < 4; ++r) acc[r] += bv;
                acc = __builtin_amdgcn_mfma_f32_16x16x32_bf16(ha0[m], w0f, acc, 0, 0, 0);
                acc = __builtin_amdgcn_mfma_f32_16x16x32_bf16(ha1[m], w1f, acc, 0, 0, 0);
                pooled[m][nt] = acc;
            }
        }
    }

    // =============== head ===================================================
    const float4 wo4 = *(const float4*)(Wout + 4 * l16);
    const float bo = bout[0];
#pragma unroll
    for (int m = 0; m < 2; ++m) {
        float o[4];
#pragma unroll
        for (int r = 0; r < 4; ++r) {
            float v = fmaxf(pooled[m][0][r], 0.f) * wo4.x
                    + fmaxf(pooled[m][1][r], 0.f) * wo4.y
                    + fmaxf(pooled[m][2][r], 0.f) * wo4.z
                    + fmaxf(pooled[m][3][r], 0.f) * wo4.w;
            v += __shfl_xor(v, 1);
            v += __shfl_xor(v, 2);
            v += __shfl_xor(v, 4);
            v += __shfl_xor(v, 8);
            o[r] = v + bo;
        }
        if (l16 == 0) {
            *(float4*)(out + (size_t)b * P + base + m * 16 + quad * 4) =
                make_float4(o[0], o[1], o[2], o[3]);
        }
    }
}

extern "C" void kernel_launch(void* const* d_in, const int* in_sizes, int n_in,
                              void* d_out, int out_size, void* d_ws, size_t ws_size,
                              hipStream_t stream) {
    const float* z      = (const float*)d_in[0];
    const float* pos    = (const float*)d_in[1];
    const float* p      = (const float*)d_in[2];
    const float* W_feat = (const float*)d_in[3];
    const float* W_dir  = (const float*)d_in[4];
    const float* W0     = (const float*)d_in[5];
    const float* b0     = (const float*)d_in[6];
    const float* Wa     = (const float*)d_in[7];
    const float* ba     = (const float*)d_in[8];
    const float* Wb     = (const float*)d_in[9];
    const float* bb     = (const float*)d_in[10];
    const float* Wout   = (const float*)d_in[11];
    const float* bout   = (const float*)d_in[12];
    float* out = (float*)d_out;

    short* wsS = (short*)d_ws;
    short* Bxt = wsS;                    // B*C*64*64 shorts
    short* Wat = wsS + 32 * 4096;        // 5*4096
    short* Wbt = Wat + 5 * 4096;         // 5*4096

    setup_kernel<<<112, 256, 0, stream>>>(z, W_dir, W0, b0, Wa, Wb, Bxt, Wat, Wbt);

    dim3 grid(P / 128, B);
    main_kernel<<<grid, 256, 0, stream>>>(p, pos, W_feat, Bxt, Wat, Wbt,
                                          ba, bb, Wout, bout, out);
}

// Round 2
// 160.134 us; speedup vs baseline: 1.4503x; 1.4503x over previous
//
#include <hip/hip_runtime.h>
#include <math.h>

#define B 4
#define P 32768
#define C 8
#define F 32
#define D 64
#define H 64
#define RS 72   // LDS row stride in shorts

typedef __attribute__((ext_vector_type(8))) short bf16x8;
typedef __attribute__((ext_vector_type(4))) float f32x4;

__device__ __forceinline__ short f2bf(float f) {
    union { float f; unsigned u; } v; v.f = f;
    unsigned r = (v.u + 0x7FFFu + ((v.u >> 16) & 1u)) >> 16;   // RNE
    return (short)r;
}

// packed f32x2 -> bf16x2 (RNE) in one VALU op
__device__ __forceinline__ unsigned cvt_pk_bf16(float lo, float hi) {
    unsigned r;
    asm("v_cvt_pk_bf16_f32 %0, %1, %2" : "=v"(r) : "v"(lo), "v"(hi));
    return r;
}

// ---------------------------------------------------------------------------
// Merged setup kernel.
// blocks [0,32):  per-(b,c) Bxt build. W_dir and W0[1..64] staged in LDS once
// (was: 1024 global loads/thread in round 0; register hoist in round 1
// spilled). blocks [32,112): Wa/Wb transpose+cvt to n-major bf16 with the
// column permutation s = (a%4)*16 + a/4.
// ---------------------------------------------------------------------------
__global__ __launch_bounds__(256)
void setup_kernel(const float* __restrict__ z,
                  const float* __restrict__ W_dir,
                  const float* __restrict__ W0,
                  const float* __restrict__ b0,
                  const float* __restrict__ Wa,
                  const float* __restrict__ Wb,
                  short* __restrict__ Bxt,
                  short* __restrict__ Wat,
                  short* __restrict__ Wbt)
{
    if (blockIdx.x >= 32) {
        int idx = (blockIdx.x - 32) * 256 + threadIdx.x;  // < 5*64*64
        int i = idx >> 12, r = idx & 4095, k = r >> 6, n = r & 63;
        int s = (n & 3) * 16 + (n >> 2);                  // permuted storage row
        int o = (i << 12) + (s << 6) + k;
        Wat[o] = f2bf(Wa[idx]);
        Wbt[o] = f2bf(Wb[idx]);
        return;
    }
    const int bc = blockIdx.x;
    const int t  = threadIdx.x & 63;     // actual output column
    const int g  = threadIdx.x >> 6;     // f-group 0..3
    const float* zb = z + (size_t)bc * F * D;

    __shared__ float zl[F][D];       // 8 KB
    __shared__ float wdir[D][D];     // 16 KB
    __shared__ float w0m[D][H];      // 16 KB (W0 rows 1..64)
    __shared__ float zp[4][D];       // 1 KB

    for (int i = threadIdx.x; i < F * D; i += 256) zl[i >> 6][i & 63] = zb[i];
    for (int i = threadIdx.x; i < D * D; i += 256) wdir[i >> 6][i & 63] = W_dir[i];
    for (int i = threadIdx.x; i < D * H; i += 256) w0m[i >> 6][i & 63] = W0[H + i];
    __syncthreads();

    const int srow = (t & 3) * 16 + (t >> 2);
    short* brow = Bxt + ((size_t)bc * 64 + srow) * 64;

    float zi = 0.f;
    for (int f = g * 8; f < g * 8 + 8; ++f) {
        float z0 = 0, z1 = 0, z2 = 0, z3 = 0;
        float a0 = 0, a1 = 0, a2 = 0, a3 = 0;
#pragma unroll
        for (int d = 0; d < D; d += 4) {
            z0 += zl[f][d + 0] * wdir[d + 0][t];
            z1 += zl[f][d + 1] * wdir[d + 1][t];
            z2 += zl[f][d + 2] * wdir[d + 2][t];
            z3 += zl[f][d + 3] * wdir[d + 3][t];
            a0 += zl[f][d + 0] * w0m[d + 0][t];
            a1 += zl[f][d + 1] * w0m[d + 1][t];
            a2 += zl[f][d + 2] * w0m[d + 2][t];
            a3 += zl[f][d + 3] * w0m[d + 3][t];
        }
        zi += zl[f][t] * ((z0 + z1) + (z2 + z3));
        brow[f] = f2bf((a0 + a1) + (a2 + a3));    // ZW row f, col t (K natural)
    }
    zp[g][t] = zi;
    __syncthreads();
    if (g == 0) {
        float zall = zp[0][t] + zp[1][t] + zp[2][t] + zp[3][t];
        zp[0][t] = zall;                          // full z_inv[t]
    }
    __syncthreads();
    if (g == 0) {
        brow[32] = f2bf(W0[t]);                   // multiplies s2
        float zc = b0[t];
        for (int e = 0; e < D; ++e) zc += zp[0][e] * W0[(65 + e) * H + t];
        brow[33] = f2bf(zc);                      // multiplies 1
    } else if (g == 1) {
        for (int k = 34; k < 64; ++k) brow[k] = 0;
    }
}

// ---------------------------------------------------------------------------
// Main: 4 waves/block; each wave owns 32 points (2 m-tiles), one channel per
// c-iter. KEY CHANGE vs r0/r1: layer-0 weight fragments (Wa0, Wb0 — both
// c-invariant) are hoisted into registers before the c-loop, and Bxt
// fragments are software-prefetched one channel ahead (issued right after
// stage-1 consumes the previous set -> a 2-LDS-round-trip + 32-MFMA window
// to land). This removes global-load latency from all c-loop stage
// boundaries, which r0/r1 could not do (no register budget: r0 192 at cap,
// r1 84 spilling). launch_bounds(256,2): cap 256, est. peak ~247, no spill.
// ---------------------------------------------------------------------------
__global__ __launch_bounds__(256, 2)
void main_kernel(const float* __restrict__ p,      // (B,P,3)
                 const float* __restrict__ pos,    // (B,3)
                 const float* __restrict__ W_feat, // (3,F)
                 const short* __restrict__ Bxt,    // (B,C,64s,64k) bf16 (perm cols)
                 const short* __restrict__ Wat,    // (5,64s,64k)
                 const short* __restrict__ Wbt,    // (5,64s,64k)
                 const float* __restrict__ ba,     // (5,H)
                 const float* __restrict__ bb,     // (5,H)
                 const float* __restrict__ Wout,   // (H,1)
                 const float* __restrict__ bout,   // (1,)
                 float* __restrict__ out)          // (B,P)
{
    const int wave = threadIdx.x >> 6;
    const int lane = threadIdx.x & 63;
    const int quad = lane >> 4;
    const int l16  = lane & 15;
    const int b    = blockIdx.y;
    const int base = blockIdx.x * 128 + wave * 32;

    __shared__ short lds[4][2][16 * RS];          // [wave][m-chain] = 18.4 KB

    // ---- point features -> A'-frags for both m-tiles
    bf16x8 a0[2], a1[2];
#pragma unroll
    for (int m = 0; m < 2; ++m) {
        const float* pp = p + ((size_t)b * P + base + m * 16 + l16) * 3;
        float px = pp[0] - pos[b * 3 + 0];
        float py = pp[1] - pos[b * 3 + 1];
        float pz = pp[2] - pos[b * 3 + 2];
        float nrm = sqrtf(px * px + py * py + pz * pz);
        if (nrm > 0.5f) { float s = 0.5f / nrm; px *= s; py *= s; pz *= s; }
        float av[8];
        float s2 = 0.f;
#pragma unroll
        for (int j = 0; j < 8; ++j) {
            int k = quad * 8 + j;
            av[j] = px * W_feat[k] + py * W_feat[F + k] + pz * W_feat[2 * F + k];
            s2 += av[j] * av[j];
        }
        s2 += __shfl_xor(s2, 16);
        s2 += __shfl_xor(s2, 32);
        union { bf16x8 v; unsigned u[4]; } ua;
#pragma unroll
        for (int j = 0; j < 4; ++j) ua.u[j] = cvt_pk_bf16(av[2 * j], av[2 * j + 1]);
        a0[m] = ua.v;
        union { bf16x8 v; unsigned u[4]; } ub;
#pragma unroll
        for (int j = 0; j < 4; ++j) ub.u[j] = 0;
        if (quad == 0) ub.u[0] = cvt_pk_bf16(s2, 1.0f);
        a1[m] = ub.v;
    }

    f32x4 pooled[2][4];
#pragma unroll
    for (int m = 0; m < 2; ++m)
#pragma unroll
        for (int nt = 0; nt < 4; ++nt)
            pooled[m][nt] = (f32x4){-1e30f, -1e30f, -1e30f, -1e30f};

    const float4 ba0v = *(const float4*)(ba + 4 * l16);
    const float4 bb0v = *(const float4*)(bb + 4 * l16);

    // ---- hoist layer-0 weight fragments (c-invariant; 64 VGPRs)
    bf16x8 wa0f[4][2], wb0f[4][2];
#pragma unroll
    for (int nt = 0; nt < 4; ++nt) {
        wa0f[nt][0] = *(const bf16x8*)(Wat + (nt * 16 + l16) * 64 + quad * 8);
        wa0f[nt][1] = *(const bf16x8*)(Wat + (nt * 16 + l16) * 64 + 32 + quad * 8);
        wb0f[nt][0] = *(const bf16x8*)(Wbt + (nt * 16 + l16) * 64 + quad * 8);
        wb0f[nt][1] = *(const bf16x8*)(Wbt + (nt * 16 + l16) * 64 + 32 + quad * 8);
    }

    // ---- prefetch c=0 Bxt fragments
    const short* bxbase = Bxt + (size_t)b * C * 4096;
    bf16x8 bxf[4][2];
#pragma unroll
    for (int nt = 0; nt < 4; ++nt) {
        bxf[nt][0] = *(const bf16x8*)(bxbase + (nt * 16 + l16) * 64 + quad * 8);
        bxf[nt][1] = *(const bf16x8*)(bxbase + (nt * 16 + l16) * 64 + 32 + quad * 8);
    }

    // =============== c-loop: 1 channel per iter, 2 m-chains =================
#pragma unroll 1
    for (int c = 0; c < C; ++c) {
        // ---- stage 1: x-build (consumes bxf)
        f32x4 x[2][4];
#pragma unroll
        for (int nt = 0; nt < 4; ++nt)
#pragma unroll
            for (int m = 0; m < 2; ++m) {
                f32x4 acc = (f32x4){0.f, 0.f, 0.f, 0.f};
                acc = __builtin_amdgcn_mfma_f32_16x16x32_bf16(a0[m], bxf[nt][0], acc, 0, 0, 0);
                acc = __builtin_amdgcn_mfma_f32_16x16x32_bf16(a1[m], bxf[nt][1], acc, 0, 0, 0);
                x[m][nt] = acc;
            }

        // ---- prefetch next channel's Bxt frags (lands during stages 2-3)
        if (c + 1 < C) {
            const short* bx = bxbase + (size_t)(c + 1) * 4096;
#pragma unroll
            for (int nt = 0; nt < 4; ++nt) {
                bxf[nt][0] = *(const bf16x8*)(bx + (nt * 16 + l16) * 64 + quad * 8);
                bxf[nt][1] = *(const bf16x8*)(bx + (nt * 16 + l16) * 64 + 32 + quad * 8);
            }
        }

        // ---- relu(x) -> LDS (b64 writes) -> A-frags
        bf16x8 xa0[2], xa1[2];
#pragma unroll
        for (int m = 0; m < 2; ++m) {
            short* buf = &lds[wave][m][0];
#pragma unroll
            for (int r = 0; r < 4; ++r) {
                uint2 w2;
                w2.x = cvt_pk_bf16(fmaxf(x[m][0][r], 0.f), fmaxf(x[m][1][r], 0.f));
                w2.y = cvt_pk_bf16(fmaxf(x[m][2][r], 0.f), fmaxf(x[m][3][r], 0.f));
                *(uint2*)(buf + (quad * 4 + r) * RS + 4 * l16) = w2;
            }
        }
#pragma unroll
        for (int m = 0; m < 2; ++m) {
            const short* buf = &lds[wave][m][0];
            xa0[m] = *(const bf16x8*)(buf + l16 * RS + quad * 8);
            xa1[m] = *(const bf16x8*)(buf + l16 * RS + 32 + quad * 8);
        }

        // ---- stage 2: h = relu(x) @ Wa0 + ba0 (hoisted frags)
        f32x4 h[2][4];
#pragma unroll
        for (int nt = 0; nt < 4; ++nt) {
            float bv = nt == 0 ? ba0v.x : nt == 1 ? ba0v.y : nt == 2 ? ba0v.z : ba0v.w;
#pragma unroll
            for (int m = 0; m < 2; ++m) {
                f32x4 acc = (f32x4){bv, bv, bv, bv};
                acc = __builtin_amdgcn_mfma_f32_16x16x32_bf16(xa0[m], wa0f[nt][0], acc, 0, 0, 0);
                acc = __builtin_amdgcn_mfma_f32_16x16x32_bf16(xa1[m], wa0f[nt][1], acc, 0, 0, 0);
                h[m][nt] = acc;
            }
        }

        // ---- relu(h) -> LDS -> A-frags
        bf16x8 ha0[2], ha1[2];
#pragma unroll
        for (int m = 0; m < 2; ++m) {
            short* buf = &lds[wave][m][0];
#pragma unroll
            for (int r = 0; r < 4; ++r) {
                uint2 w2;
                w2.x = cvt_pk_bf16(fmaxf(h[m][0][r], 0.f), fmaxf(h[m][1][r], 0.f));
                w2.y = cvt_pk_bf16(fmaxf(h[m][2][r], 0.f), fmaxf(h[m][3][r], 0.f));
                *(uint2*)(buf + (quad * 4 + r) * RS + 4 * l16) = w2;
            }
        }
#pragma unroll
        for (int m = 0; m < 2; ++m) {
            const short* buf = &lds[wave][m][0];
            ha0[m] = *(const bf16x8*)(buf + l16 * RS + quad * 8);
            ha1[m] = *(const bf16x8*)(buf + l16 * RS + 32 + quad * 8);
        }

        // ---- stage 3: x += bb0 + relu(h) @ Wb0 ; max-pool over c
#pragma unroll
        for (int nt = 0; nt < 4; ++nt) {
            float bv = nt == 0 ? bb0v.x : nt == 1 ? bb0v.y : nt == 2 ? bb0v.z : bb0v.w;
#pragma unroll
            for (int m = 0; m < 2; ++m) {
                f32x4 acc = x[m][nt];
#pragma unroll
                for (int r = 0; r < 4; ++r) acc[r] += bv;
                acc = __builtin_amdgcn_mfma_f32_16x16x32_bf16(ha0[m], wb0f[nt][0], acc, 0, 0, 0);
                acc = __builtin_amdgcn_mfma_f32_16x16x32_bf16(ha1[m], wb0f[nt][1], acc, 0, 0, 0);
#pragma unroll
                for (int r = 0; r < 4; ++r)
                    pooled[m][nt][r] = fmaxf(pooled[m][nt][r], acc[r]);
            }
        }
    }

    // =============== residual blocks 1..4 (2 chains: m-tiles) ===============
#pragma unroll
    for (int i = 1; i < 5; ++i) {
        const short* wa = Wat + i * 4096;
        const short* wb = Wbt + i * 4096;
        const float4 bai = *(const float4*)(ba + i * H + 4 * l16);
        const float4 bbi = *(const float4*)(bb + i * H + 4 * l16);

        bf16x8 xa0[2], xa1[2];
#pragma unroll
        for (int m = 0; m < 2; ++m) {
            short* buf = &lds[wave][m][0];
#pragma unroll
            for (int r = 0; r < 4; ++r) {
                uint2 w2;
                w2.x = cvt_pk_bf16(fmaxf(pooled[m][0][r], 0.f), fmaxf(pooled[m][1][r], 0.f));
                w2.y = cvt_pk_bf16(fmaxf(pooled[m][2][r], 0.f), fmaxf(pooled[m][3][r], 0.f));
                *(uint2*)(buf + (quad * 4 + r) * RS + 4 * l16) = w2;
            }
        }
#pragma unroll
        for (int m = 0; m < 2; ++m) {
            const short* buf = &lds[wave][m][0];
            xa0[m] = *(const bf16x8*)(buf + l16 * RS + quad * 8);
            xa1[m] = *(const bf16x8*)(buf + l16 * RS + 32 + quad * 8);
        }

        f32x4 h[2][4];
#pragma unroll
        for (int nt = 0; nt < 4; ++nt) {
            bf16x8 w0f = *(const bf16x8*)(wa + (nt * 16 + l16) * 64 + quad * 8);
            bf16x8 w1f = *(const bf16x8*)(wa + (nt * 16 + l16) * 64 + 32 + quad * 8);
            float bv = nt == 0 ? bai.x : nt == 1 ? bai.y : nt == 2 ? bai.z : bai.w;
#pragma unroll
            for (int m = 0; m < 2; ++m) {
                f32x4 acc = (f32x4){bv, bv, bv, bv};
                acc = __builtin_amdgcn_mfma_f32_16x16x32_bf16(xa0[m], w0f, acc, 0, 0, 0);
                acc = __builtin_amdgcn_mfma_f32_16x16x32_bf16(xa1[m], w1f, acc, 0, 0, 0);
                h[m][nt] = acc;
            }
        }

        bf16x8 ha0[2], ha1[2];
#pragma unroll
        for (int m = 0; m < 2; ++m) {
            short* buf = &lds[wave][m][0];
#pragma unroll
            for (int r = 0; r < 4; ++r) {
                uint2 w2;
                w2.x = cvt_pk_bf16(fmaxf(h[m][0][r], 0.f), fmaxf(h[m][1][r], 0.f));
                w2.y = cvt_pk_bf16(fmaxf(h[m][2][r], 0.f), fmaxf(h[m][3][r], 0.f));
                *(uint2*)(buf + (quad * 4 + r) * RS + 4 * l16) = w2;
            }
        }
#pragma unroll
        for (int m = 0; m < 2; ++m) {
            const short* buf = &lds[wave][m][0];
            ha0[m] = *(const bf16x8*)(buf + l16 * RS + quad * 8);
            ha1[m] = *(const bf16x8*)(buf + l16 * RS + 32 + quad * 8);
        }

#pragma unroll
        for (int nt = 0; nt < 4; ++nt) {
            bf16x8 w0f = *(const bf16x8*)(wb + (nt * 16 + l16) * 64 + quad * 8);
            bf16x8 w1f = *(const bf16x8*)(wb + (nt * 16 + l16) * 64 + 32 + quad * 8);
            float bv = nt == 0 ? bbi.x : nt == 1 ? bbi.y : nt == 2 ? bbi.z : bbi.w;
#pragma unroll
            for (int m = 0; m < 2; ++m) {
                f32x4 acc = pooled[m][nt];
#pragma unroll
                for (int r = 0; r < 4; ++r) acc[r] += bv;
                acc = __builtin_amdgcn_mfma_f32_16x16x32_bf16(ha0[m], w0f, acc, 0, 0, 0);
                acc = __builtin_amdgcn_mfma_f32_16x16x32_bf16(ha1[m], w1f, acc, 0, 0, 0);
                pooled[m][nt] = acc;
            }
        }
    }

    // =============== head ===================================================
    const float4 wo4 = *(const float4*)(Wout + 4 * l16);
    const float bo = bout[0];
#pragma unroll
    for (int m = 0; m < 2; ++m) {
        float o[4];
#pragma unroll
        for (int r = 0; r < 4; ++r) {
            float v = fmaxf(pooled[m][0][r], 0.f) * wo4.x
                    + fmaxf(pooled[m][1][r], 0.f) * wo4.y
                    + fmaxf(pooled[m][2][r], 0.f) * wo4.z
                    + fmaxf(pooled[m][3][r], 0.f) * wo4.w;
            v += __shfl_xor(v, 1);
            v += __shfl_xor(v, 2);
            v += __shfl_xor(v, 4);
            v += __shfl_xor(v, 8);
            o[r] = v + bo;
        }
        if (l16 == 0) {
            *(float4*)(out + (size_t)b * P + base + m * 16 + quad * 4) =
                make_float4(o[0], o[1], o[2], o[3]);
        }
    }
}

extern "C" void kernel_launch(void* const* d_in, const int* in_sizes, int n_in,
                              void* d_out, int out_size, void* d_ws, size_t ws_size,
                              hipStream_t stream) {
    const float* z      = (const float*)d_in[0];
    const float* pos    = (const float*)d_in[1];
    const float* p      = (const float*)d_in[2];
    const float* W_feat = (const float*)d_in[3];
    const float* W_dir  = (const float*)d_in[4];
    const float* W0     = (const float*)d_in[5];
    const float* b0     = (const float*)d_in[6];
    const float* Wa     = (const float*)d_in[7];
    const float* ba     = (const float*)d_in[8];
    const float* Wb     = (const float*)d_in[9];
    const float* bb     = (const float*)d_in[10];
    const float* Wout   = (const float*)d_in[11];
    const float* bout   = (const float*)d_in[12];
    float* out = (float*)d_out;

    short* wsS = (short*)d_ws;
    short* Bxt = wsS;                    // B*C*64*64 shorts
    short* Wat = wsS + 32 * 4096;        // 5*4096
    short* Wbt = Wat + 5 * 4096;         // 5*4096

    setup_kernel<<<112, 256, 0, stream>>>(z, W_dir, W0, b0, Wa, Wb, Bxt, Wat, Wbt);

    dim3 grid(P / 128, B);
    main_kernel<<<grid, 256, 0, stream>>>(p, pos, W_feat, Bxt, Wat, Wbt,
                                          ba, bb, Wout, bout, out);
}

// Round 3
// 146.771 us; speedup vs baseline: 1.5824x; 1.0910x over previous
//
#include <hip/hip_runtime.h>
#include <math.h>

#define B 4
#define P 32768
#define C 8
#define F 32
#define D 64
#define H 64
#define RS 72   // LDS row stride in shorts (transform buffers)

typedef __attribute__((ext_vector_type(8))) short bf16x8;
typedef __attribute__((ext_vector_type(4))) float f32x4;

__device__ __forceinline__ short f2bf(float f) {
    union { float f; unsigned u; } v; v.f = f;
    unsigned r = (v.u + 0x7FFFu + ((v.u >> 16) & 1u)) >> 16;   // RNE
    return (short)r;
}

// packed f32x2 -> bf16x2 (RNE) in one VALU op
__device__ __forceinline__ unsigned cvt_pk_bf16(float lo, float hi) {
    unsigned r;
    asm("v_cvt_pk_bf16_f32 %0, %1, %2" : "=v"(r) : "v"(lo), "v"(hi));
    return r;
}

// async global->LDS, 16B per lane. LDS dest = wave-uniform base + lane*16;
// global src = per-lane address (guide §5).
__device__ __forceinline__ void gload_lds16(const void* g, void* s) {
    __builtin_amdgcn_global_load_lds(
        (const __attribute__((address_space(1))) unsigned*)g,
        (__attribute__((address_space(3))) unsigned*)s, 16, 0, 0);
}

// ---------------------------------------------------------------------------
// Merged setup kernel.
// blocks [0,32):  per-(b,c) Bxt build. Bxt rows are stored with the XOR
// swizzle  short_idx ^= (row&7)<<3  so that main_kernel's ds_read_b128 frag
// reads from the LDS-staged copy are bank-conflict-free (rule #21: swizzle
// baked into the global source; global_load_lds copies linearly).
// blocks [32,112): Wa/Wb transpose+cvt to n-major bf16 with the column
// permutation s = (a%4)*16 + a/4 (NOT swizzled — read via regs from global).
// ---------------------------------------------------------------------------
__global__ __launch_bounds__(256)
void setup_kernel(const float* __restrict__ z,
                  const float* __restrict__ W_dir,
                  const float* __restrict__ W0,
                  const float* __restrict__ b0,
                  const float* __restrict__ Wa,
                  const float* __restrict__ Wb,
                  short* __restrict__ Bxt,
                  short* __restrict__ Wat,
                  short* __restrict__ Wbt)
{
    if (blockIdx.x >= 32) {
        int idx = (blockIdx.x - 32) * 256 + threadIdx.x;  // < 5*64*64
        int i = idx >> 12, r = idx & 4095, k = r >> 6, n = r & 63;
        int s = (n & 3) * 16 + (n >> 2);                  // permuted storage row
        int o = (i << 12) + (s << 6) + k;
        Wat[o] = f2bf(Wa[idx]);
        Wbt[o] = f2bf(Wb[idx]);
        return;
    }
    const int bc = blockIdx.x;
    const int t  = threadIdx.x & 63;     // actual output column
    const int g  = threadIdx.x >> 6;     // f-group 0..3
    const float* zb = z + (size_t)bc * F * D;

    __shared__ float zl[F][D];       // 8 KB
    __shared__ float wdir[D][D];     // 16 KB
    __shared__ float w0m[D][H];      // 16 KB (W0 rows 1..64)
    __shared__ float zp[4][D];       // 1 KB
    __shared__ float zq[4][D];       // 1 KB

    for (int i = threadIdx.x; i < F * D; i += 256) zl[i >> 6][i & 63] = zb[i];
    for (int i = threadIdx.x; i < D * D; i += 256) wdir[i >> 6][i & 63] = W_dir[i];
    for (int i = threadIdx.x; i < D * H; i += 256) w0m[i >> 6][i & 63] = W0[H + i];
    __syncthreads();

    const int srow = (t & 3) * 16 + (t >> 2);
    const int sw   = (srow & 7) << 3;                 // bank swizzle (shorts)
    short* brow = Bxt + ((size_t)bc * 64 + srow) * 64;

    float zi = 0.f;
    for (int f = g * 8; f < g * 8 + 8; ++f) {
        float z0 = 0, z1 = 0, z2 = 0, z3 = 0;
        float a0 = 0, a1 = 0, a2 = 0, a3 = 0;
#pragma unroll
        for (int d = 0; d < D; d += 4) {
            float4 z4 = *(const float4*)&zl[f][d];    // broadcast b128
            z0 += z4.x * wdir[d + 0][t];
            z1 += z4.y * wdir[d + 1][t];
            z2 += z4.z * wdir[d + 2][t];
            z3 += z4.w * wdir[d + 3][t];
            a0 += z4.x * w0m[d + 0][t];
            a1 += z4.y * w0m[d + 1][t];
            a2 += z4.z * w0m[d + 2][t];
            a3 += z4.w * w0m[d + 3][t];
        }
        zi += zl[f][t] * ((z0 + z1) + (z2 + z3));
        brow[f ^ sw] = f2bf((a0 + a1) + (a2 + a3));   // ZW row f, col t
    }
    zp[g][t] = zi;
    __syncthreads();
    if (g == 0) {
        float zall = zp[0][t] + zp[1][t] + zp[2][t] + zp[3][t];
        zp[0][t] = zall;                              // full z_inv[t]
    }
    __syncthreads();
    // zc partials: each g-group covers 16 e's (was: 64-iter serial loop on g==0)
    {
        float zcp = 0.f;
        for (int e = g * 16; e < g * 16 + 16; ++e)
            zcp += zp[0][e] * W0[(65 + e) * H + t];
        zq[g][t] = zcp;
    }
    __syncthreads();
    if (g == 0) {
        brow[32 ^ sw] = f2bf(W0[t]);                  // multiplies s2
        float zc = b0[t] + zq[0][t] + zq[1][t] + zq[2][t] + zq[3][t];
        brow[33 ^ sw] = f2bf(zc);                     // multiplies 1
    } else if (g == 1) {
        for (int k = 34; k < 64; ++k) brow[k ^ sw] = 0;
    }
}

// ---------------------------------------------------------------------------
// Main: 4 waves/block; each wave owns 32 points (2 m-tiles), one channel per
// c-iter. KEY CHANGE vs r2: Bxt fragments no longer live in per-wave VGPRs
// (32 regs, identical across the 4 waves!) — they are staged one channel
// ahead into block-shared LDS (double-buffered, global_load_lds x2/wave) and
// read per-stage with swizzled ds_read_b128 (conflict-free). Frees 32
// persistent VGPRs -> no spill inside the 128-reg / 16-waves-per-CU bucket.
// One __syncthreads per c-iter publishes the staged buffer (waves are
// same-length; barrier cost is small).
// ---------------------------------------------------------------------------
__global__ __launch_bounds__(256, 2)
void main_kernel(const float* __restrict__ p,      // (B,P,3)
                 const float* __restrict__ pos,    // (B,3)
                 const float* __restrict__ W_feat, // (3,F)
                 const short* __restrict__ Bxt,    // (B,C,64s,64k) bf16 (perm+swz)
                 const short* __restrict__ Wat,    // (5,64s,64k)
                 const short* __restrict__ Wbt,    // (5,64s,64k)
                 const float* __restrict__ ba,     // (5,H)
                 const float* __restrict__ bb,     // (5,H)
                 const float* __restrict__ Wout,   // (H,1)
                 const float* __restrict__ bout,   // (1,)
                 float* __restrict__ out)          // (B,P)
{
    const int wave = threadIdx.x >> 6;
    const int lane = threadIdx.x & 63;
    const int quad = lane >> 4;
    const int l16  = lane & 15;
    const int b    = blockIdx.y;
    const int base = blockIdx.x * 128 + wave * 32;

    __shared__ short lds[4][2][16 * RS];                       // 18.4 KB
    __shared__ __attribute__((aligned(16))) short bxlds[2][4096]; // 16 KB dbuf

    const short* bxg = Bxt + (size_t)b * C * 4096;

    // ---- issue staging of c=0 immediately (lands under the preamble)
    {
        const short* src = bxg + (wave * 2) * 512 + lane * 8;
        gload_lds16(src,       &bxlds[0][(wave * 2) * 512]);
        gload_lds16(src + 512, &bxlds[0][(wave * 2 + 1) * 512]);
    }

    // ---- point features -> A'-frags for both m-tiles
    bf16x8 a0[2], a1[2];
#pragma unroll
    for (int m = 0; m < 2; ++m) {
        const float* pp = p + ((size_t)b * P + base + m * 16 + l16) * 3;
        float px = pp[0] - pos[b * 3 + 0];
        float py = pp[1] - pos[b * 3 + 1];
        float pz = pp[2] - pos[b * 3 + 2];
        float nrm = sqrtf(px * px + py * py + pz * pz);
        if (nrm > 0.5f) { float s = 0.5f / nrm; px *= s; py *= s; pz *= s; }
        float av[8];
        float s2 = 0.f;
#pragma unroll
        for (int j = 0; j < 8; ++j) {
            int k = quad * 8 + j;
            av[j] = px * W_feat[k] + py * W_feat[F + k] + pz * W_feat[2 * F + k];
            s2 += av[j] * av[j];
        }
        s2 += __shfl_xor(s2, 16);
        s2 += __shfl_xor(s2, 32);
        union { bf16x8 v; unsigned u[4]; } ua;
#pragma unroll
        for (int j = 0; j < 4; ++j) ua.u[j] = cvt_pk_bf16(av[2 * j], av[2 * j + 1]);
        a0[m] = ua.v;
        union { bf16x8 v; unsigned u[4]; } ub;
#pragma unroll
        for (int j = 0; j < 4; ++j) ub.u[j] = 0;
        if (quad == 0) ub.u[0] = cvt_pk_bf16(s2, 1.0f);
        a1[m] = ub.v;
    }

    f32x4 pooled[2][4];
#pragma unroll
    for (int m = 0; m < 2; ++m)
#pragma unroll
        for (int nt = 0; nt < 4; ++nt)
            pooled[m][nt] = (f32x4){-1e30f, -1e30f, -1e30f, -1e30f};

    const float4 ba0v = *(const float4*)(ba + 4 * l16);
    const float4 bb0v = *(const float4*)(bb + 4 * l16);

    // ---- hoist layer-0 weight fragments (c-invariant; 64 VGPRs)
    bf16x8 wa0f[4][2], wb0f[4][2];
#pragma unroll
    for (int nt = 0; nt < 4; ++nt) {
        wa0f[nt][0] = *(const bf16x8*)(Wat + (nt * 16 + l16) * 64 + quad * 8);
        wa0f[nt][1] = *(const bf16x8*)(Wat + (nt * 16 + l16) * 64 + 32 + quad * 8);
        wb0f[nt][0] = *(const bf16x8*)(Wbt + (nt * 16 + l16) * 64 + quad * 8);
        wb0f[nt][1] = *(const bf16x8*)(Wbt + (nt * 16 + l16) * 64 + 32 + quad * 8);
    }

    __syncthreads();   // drains vmcnt: bxlds[0] is published

    // =============== c-loop: 1 channel per iter, 2 m-chains =================
#pragma unroll 1
    for (int c = 0; c < C; ++c) {
        // ---- issue staging for c+1 into the other buffer (lands during
        //      stages 1-3; safe: that buffer's readers finished last iter,
        //      sealed by the end-of-iter barrier)
        if (c + 1 < C) {
            const short* src = bxg + (size_t)(c + 1) * 4096 + (wave * 2) * 512 + lane * 8;
            gload_lds16(src,       &bxlds[(c + 1) & 1][(wave * 2) * 512]);
            gload_lds16(src + 512, &bxlds[(c + 1) & 1][(wave * 2 + 1) * 512]);
        }
        const short* bxs = &bxlds[c & 1][0];

        // ---- stage 1: x-build (B-frags from swizzled LDS, conflict-free)
        f32x4 x[2][4];
#pragma unroll
        for (int nt = 0; nt < 4; ++nt) {
            const int row = nt * 16 + l16;
            const int sw  = (row & 7) << 3;
            bf16x8 b0f = *(const bf16x8*)(bxs + row * 64 + ((quad * 8) ^ sw));
            bf16x8 b1f = *(const bf16x8*)(bxs + row * 64 + ((32 + quad * 8) ^ sw));
#pragma unroll
            for (int m = 0; m < 2; ++m) {
                f32x4 acc = (f32x4){0.f, 0.f, 0.f, 0.f};
                acc = __builtin_amdgcn_mfma_f32_16x16x32_bf16(a0[m], b0f, acc, 0, 0, 0);
                acc = __builtin_amdgcn_mfma_f32_16x16x32_bf16(a1[m], b1f, acc, 0, 0, 0);
                x[m][nt] = acc;
            }
        }

        // ---- relu(x) -> LDS (b64 writes) -> A-frags
        bf16x8 xa0[2], xa1[2];
#pragma unroll
        for (int m = 0; m < 2; ++m) {
            short* buf = &lds[wave][m][0];
#pragma unroll
            for (int r = 0; r < 4; ++r) {
                uint2 w2;
                w2.x = cvt_pk_bf16(fmaxf(x[m][0][r], 0.f), fmaxf(x[m][1][r], 0.f));
                w2.y = cvt_pk_bf16(fmaxf(x[m][2][r], 0.f), fmaxf(x[m][3][r], 0.f));
                *(uint2*)(buf + (quad * 4 + r) * RS + 4 * l16) = w2;
            }
        }
#pragma unroll
        for (int m = 0; m < 2; ++m) {
            const short* buf = &lds[wave][m][0];
            xa0[m] = *(const bf16x8*)(buf + l16 * RS + quad * 8);
            xa1[m] = *(const bf16x8*)(buf + l16 * RS + 32 + quad * 8);
        }

        // ---- stage 2: h = relu(x) @ Wa0 + ba0 (hoisted frags)
        f32x4 h[2][4];
#pragma unroll
        for (int nt = 0; nt < 4; ++nt) {
            float bv = nt == 0 ? ba0v.x : nt == 1 ? ba0v.y : nt == 2 ? ba0v.z : ba0v.w;
#pragma unroll
            for (int m = 0; m < 2; ++m) {
                f32x4 acc = (f32x4){bv, bv, bv, bv};
                acc = __builtin_amdgcn_mfma_f32_16x16x32_bf16(xa0[m], wa0f[nt][0], acc, 0, 0, 0);
                acc = __builtin_amdgcn_mfma_f32_16x16x32_bf16(xa1[m], wa0f[nt][1], acc, 0, 0, 0);
                h[m][nt] = acc;
            }
        }

        // ---- relu(h) -> LDS -> A-frags
        bf16x8 ha0[2], ha1[2];
#pragma unroll
        for (int m = 0; m < 2; ++m) {
            short* buf = &lds[wave][m][0];
#pragma unroll
            for (int r = 0; r < 4; ++r) {
                uint2 w2;
                w2.x = cvt_pk_bf16(fmaxf(h[m][0][r], 0.f), fmaxf(h[m][1][r], 0.f));
                w2.y = cvt_pk_bf16(fmaxf(h[m][2][r], 0.f), fmaxf(h[m][3][r], 0.f));
                *(uint2*)(buf + (quad * 4 + r) * RS + 4 * l16) = w2;
            }
        }
#pragma unroll
        for (int m = 0; m < 2; ++m) {
            const short* buf = &lds[wave][m][0];
            ha0[m] = *(const bf16x8*)(buf + l16 * RS + quad * 8);
            ha1[m] = *(const bf16x8*)(buf + l16 * RS + 32 + quad * 8);
        }

        // ---- stage 3: x += bb0 + relu(h) @ Wb0 ; max-pool over c
#pragma unroll
        for (int nt = 0; nt < 4; ++nt) {
            float bv = nt == 0 ? bb0v.x : nt == 1 ? bb0v.y : nt == 2 ? bb0v.z : bb0v.w;
#pragma unroll
            for (int m = 0; m < 2; ++m) {
                f32x4 acc = x[m][nt];
#pragma unroll
                for (int r = 0; r < 4; ++r) acc[r] += bv;
                acc = __builtin_amdgcn_mfma_f32_16x16x32_bf16(ha0[m], wb0f[nt][0], acc, 0, 0, 0);
                acc = __builtin_amdgcn_mfma_f32_16x16x32_bf16(ha1[m], wb0f[nt][1], acc, 0, 0, 0);
#pragma unroll
                for (int r = 0; r < 4; ++r)
                    pooled[m][nt][r] = fmaxf(pooled[m][nt][r], acc[r]);
            }
        }

        __syncthreads();   // publishes staged buffer for next iter
    }

    // =============== residual blocks 1..4 (2 chains: m-tiles) ===============
#pragma unroll
    for (int i = 1; i < 5; ++i) {
        const short* wa = Wat + i * 4096;
        const short* wb = Wbt + i * 4096;
        const float4 bai = *(const float4*)(ba + i * H + 4 * l16);
        const float4 bbi = *(const float4*)(bb + i * H + 4 * l16);

        bf16x8 xa0[2], xa1[2];
#pragma unroll
        for (int m = 0; m < 2; ++m) {
            short* buf = &lds[wave][m][0];
#pragma unroll
            for (int r = 0; r < 4; ++r) {
                uint2 w2;
                w2.x = cvt_pk_bf16(fmaxf(pooled[m][0][r], 0.f), fmaxf(pooled[m][1][r], 0.f));
                w2.y = cvt_pk_bf16(fmaxf(pooled[m][2][r], 0.f), fmaxf(pooled[m][3][r], 0.f));
                *(uint2*)(buf + (quad * 4 + r) * RS + 4 * l16) = w2;
            }
        }
#pragma unroll
        for (int m = 0; m < 2; ++m) {
            const short* buf = &lds[wave][m][0];
            xa0[m] = *(const bf16x8*)(buf + l16 * RS + quad * 8);
            xa1[m] = *(const bf16x8*)(buf + l16 * RS + 32 + quad * 8);
        }

        f32x4 h[2][4];
#pragma unroll
        for (int nt = 0; nt < 4; ++nt) {
            bf16x8 w0f = *(const bf16x8*)(wa + (nt * 16 + l16) * 64 + quad * 8);
            bf16x8 w1f = *(const bf16x8*)(wa + (nt * 16 + l16) * 64 + 32 + quad * 8);
            float bv = nt == 0 ? bai.x : nt == 1 ? bai.y : nt == 2 ? bai.z : bai.w;
#pragma unroll
            for (int m = 0; m < 2; ++m) {
                f32x4 acc = (f32x4){bv, bv, bv, bv};
                acc = __builtin_amdgcn_mfma_f32_16x16x32_bf16(xa0[m], w0f, acc, 0, 0, 0);
                acc = __builtin_amdgcn_mfma_f32_16x16x32_bf16(xa1[m], w1f, acc, 0, 0, 0);
                h[m][nt] = acc;
            }
        }

        bf16x8 ha0[2], ha1[2];
#pragma unroll
        for (int m = 0; m < 2; ++m) {
            short* buf = &lds[wave][m][0];
#pragma unroll
            for (int r = 0; r < 4; ++r) {
                uint2 w2;
                w2.x = cvt_pk_bf16(fmaxf(h[m][0][r], 0.f), fmaxf(h[m][1][r], 0.f));
                w2.y = cvt_pk_bf16(fmaxf(h[m][2][r], 0.f), fmaxf(h[m][3][r], 0.f));
                *(uint2*)(buf + (quad * 4 + r) * RS + 4 * l16) = w2;
            }
        }
#pragma unroll
        for (int m = 0; m < 2; ++m) {
            const short* buf = &lds[wave][m][0];
            ha0[m] = *(const bf16x8*)(buf + l16 * RS + quad * 8);
            ha1[m] = *(const bf16x8*)(buf + l16 * RS + 32 + quad * 8);
        }

#pragma unroll
        for (int nt = 0; nt < 4; ++nt) {
            bf16x8 w0f = *(const bf16x8*)(wb + (nt * 16 + l16) * 64 + quad * 8);
            bf16x8 w1f = *(const bf16x8*)(wb + (nt * 16 + l16) * 64 + 32 + quad * 8);
            float bv = nt == 0 ? bbi.x : nt == 1 ? bbi.y : nt == 2 ? bbi.z : bbi.w;
#pragma unroll
            for (int m = 0; m < 2; ++m) {
                f32x4 acc = pooled[m][nt];
#pragma unroll
                for (int r = 0; r < 4; ++r) acc[r] += bv;
                acc = __builtin_amdgcn_mfma_f32_16x16x32_bf16(ha0[m], w0f, acc, 0, 0, 0);
                acc = __builtin_amdgcn_mfma_f32_16x16x32_bf16(ha1[m], w1f, acc, 0, 0, 0);
                pooled[m][nt] = acc;
            }
        }
    }

    // =============== head ===================================================
    const float4 wo4 = *(const float4*)(Wout + 4 * l16);
    const float bo = bout[0];
#pragma unroll
    for (int m = 0; m < 2; ++m) {
        float o[4];
#pragma unroll
        for (int r = 0; r < 4; ++r) {
            float v = fmaxf(pooled[m][0][r], 0.f) * wo4.x
                    + fmaxf(pooled[m][1][r], 0.f) * wo4.y
                    + fmaxf(pooled[m][2][r], 0.f) * wo4.z
                    + fmaxf(pooled[m][3][r], 0.f) * wo4.w;
            v += __shfl_xor(v, 1);
            v += __shfl_xor(v, 2);
            v += __shfl_xor(v, 4);
            v += __shfl_xor(v, 8);
            o[r] = v + bo;
        }
        if (l16 == 0) {
            *(float4*)(out + (size_t)b * P + base + m * 16 + quad * 4) =
                make_float4(o[0], o[1], o[2], o[3]);
        }
    }
}

extern "C" void kernel_launch(void* const* d_in, const int* in_sizes, int n_in,
                              void* d_out, int out_size, void* d_ws, size_t ws_size,
                              hipStream_t stream) {
    const float* z      = (const float*)d_in[0];
    const float* pos    = (const float*)d_in[1];
    const float* p      = (const float*)d_in[2];
    const float* W_feat = (const float*)d_in[3];
    const float* W_dir  = (const float*)d_in[4];
    const float* W0     = (const float*)d_in[5];
    const float* b0     = (const float*)d_in[6];
    const float* Wa     = (const float*)d_in[7];
    const float* ba     = (const float*)d_in[8];
    const float* Wb     = (const float*)d_in[9];
    const float* bb     = (const float*)d_in[10];
    const float* Wout   = (const float*)d_in[11];
    const float* bout   = (const float*)d_in[12];
    float* out = (float*)d_out;

    short* wsS = (short*)d_ws;
    short* Bxt = wsS;                    // B*C*64*64 shorts
    short* Wat = wsS + 32 * 4096;        // 5*4096
    short* Wbt = Wat + 5 * 4096;         // 5*4096

    setup_kernel<<<112, 256, 0, stream>>>(z, W_dir, W0, b0, Wa, Wb, Bxt, Wat, Wbt);

    dim3 grid(P / 128, B);
    main_kernel<<<grid, 256, 0, stream>>>(p, pos, W_feat, Bxt, Wat, Wbt,
                                          ba, bb, Wout, bout, out);
}